// Round 15
// baseline (772.520 us; speedup 1.0000x reference)
//
#include <hip/hip_runtime.h>
#include <hip/hip_bf16.h>
#include <cstdint>

#define NB    16384
#define DIMX  2048
#define STATE 2048
#define SELH  1024

typedef unsigned short u16;
typedef short  short8_t __attribute__((ext_vector_type(8)));
typedef float  f32x4    __attribute__((ext_vector_type(4)));

__device__ __forceinline__ u16 f2bf(float f) {
  unsigned u = __builtin_bit_cast(unsigned, f);
  u += 0x7fffu + ((u >> 16) & 1u);   // RNE
  return (u16)(u >> 16);
}
__device__ __forceinline__ float bf2f(u16 h) {
  unsigned u = ((unsigned)h) << 16;
  return __builtin_bit_cast(float, u);
}
__device__ __forceinline__ float sigmoidf_(float x) { return 1.f / (1.f + __expf(-x)); }
__device__ __forceinline__ float tanhf_(float x)    { return 2.f / (1.f + __expf(-2.f * x)) - 1.f; }

__device__ __forceinline__ f32x4 mfma_bf16(short8_t a, short8_t b, f32x4 c) {
  return __builtin_amdgcn_mfma_f32_16x16x32_bf16(a, b, c, 0, 0, 0);
}

// ---- async global->LDS, 16B per lane ----
__device__ __forceinline__ void gload16(const void* g, const void* l) {
  __builtin_amdgcn_global_load_lds(
      (const __attribute__((address_space(1))) unsigned int*)(uintptr_t)g,
      (__attribute__((address_space(3))) unsigned int*)(unsigned int)(uintptr_t)l,
      16, 0, 0);
}

// aligned LDS vector read (ensure ds_read_b128)
#define LDS_V(p) (*(const short8_t*)__builtin_assume_aligned((const void*)(p), 16))

// ---- single-launch f32 -> bf16 convert over 5 segments ----
__global__ __launch_bounds__(256) void k_convert5(const float* __restrict__ s0, u16* __restrict__ d0, int n0,
                                                  const float* __restrict__ s1, u16* __restrict__ d1, int n1,
                                                  const float* __restrict__ s2, u16* __restrict__ d2, int n2,
                                                  const float* __restrict__ s3, u16* __restrict__ d3, int n3,
                                                  const float* __restrict__ s4, u16* __restrict__ d4, int n4) {
  const int base = blockIdx.x * blockDim.x + threadIdx.x;
  const int stride = gridDim.x * blockDim.x;
#define SEG(S, D, N)                                                     \
  for (int i = base; i < (N); i += stride) {                             \
    float4 v = ((const float4*)(S))[i];                                  \
    ushort4 o;                                                           \
    o.x = f2bf(v.x); o.y = f2bf(v.y); o.z = f2bf(v.z); o.w = f2bf(v.w);  \
    ((ushort4*)(D))[i] = o;                                              \
  }
  SEG(s0, d0, n0) SEG(s1, d1, n1) SEG(s2, d2, n2) SEG(s3, d3, n3) SEG(s4, d4, n4)
#undef SEG
}

// =====================================================================
// 128x512 GEMM tile, BK=32, 3-buffer pipeline (R6-proven sync skeleton).
// Rationale: all 256^2 variants were STAGING-BW bound (~6 TB/s L3/HBM
// service ceiling: 64KB staged per 8.4 MFLOP). BN=512 cuts the A-restage
// factor (A-bytes x N/512) and keeps B-panels (1-2 MB) L2-pinned per XCD
// via natural round-robin (gx in {2,4,16} all balance on 8 XCDs).
// 512 thr = 8 waves (2Mr x 4Nc); per-wave 64x128 = 4mf x 8nf; acc 128 VGPR.
// LDS: 3 bufs x 40KB (A [128r][32k] at +0, B [512r][32k] at +8192);
// 64B rows, read swz = ((l>>4)*16)^((l&3)<<4), stage k-slot
// ((tid&3)^((tid>>2)&3))*8 (proven pair from R9/R13).
// Per tile t: {dsread(buf t); stage(t+2 -> buf (t+2)%3); lgkmcnt(0);
//              vmcnt(5) [t+1's 5 loads landed, t+2 in flight];
//              sched_barrier; s_barrier; 32 MFMA}.
// EPI: 0 bf16 | 1 silu->bf16 | 2 f32
//      3 FUSED gate, BN_state=128: B row r -> quad ((r>>5)&3) at state col
//        bx*128+(r>>7)*32+((r>>4)&1)*16+(r&15). Wave wc frag nf: quad nf>>1,
//        col wc*32+(nf&1)*16 -> (a,b,c,d) = acc[mf][{0,2,4,6}+j] reg-local.
// =====================================================================
template <int EPI, int KD, int NCOLS>
__global__ __launch_bounds__(512, 2) void k_gemm(const u16* __restrict__ A,
                                                 const u16* __restrict__ Bsrc,
                                                 float* __restrict__ f32out,
                                                 u16* __restrict__ bfout,
                                                 const float* __restrict__ hprev,
                                                 const u16* __restrict__ ubf,
                                                 const float* __restrict__ dvec) {
  __shared__ __align__(16) char smem[122880];   // 3 x 40960
  const int tid = threadIdx.x;
  const int w = tid >> 6, l = tid & 63;
  const int wr = w >> 2, wc = w & 3;
  const int bx = blockIdx.x, by = blockIdx.y;
  const int m0 = by * 128;

  // ---- ds_read bases (swizzled, 64B rows) ----
  const unsigned sx = (unsigned)(((l >> 4) * 16) ^ ((l & 3) << 4));
  const unsigned aAddr = (unsigned)((wr * 64 + (l & 15)) * 64) + sx;            // +mf*1024
  const unsigned bAddr = 8192u + (unsigned)((wc * 128 + (l & 15)) * 64) + sx;   // +nf*1024

  // ---- staging sources (inverse-swizzled) ----
  const int rT = tid >> 2;                       // 0..127
  const int kT = ((tid & 3) ^ (rT & 3)) * 8;     // k-elem offset
  const u16* aSrc = A + (size_t)(m0 + rT) * KD + kT;
  const u16* bSrcP[4];
#pragma unroll
  for (int g = 0; g < 4; ++g) {
    const int r = g * 128 + rT;                  // B tile row 0..511
    size_t wrow;
    if constexpr (EPI != 3) {
      wrow = (size_t)bx * 512 + r;
    } else {
      wrow = (size_t)((r >> 5) & 3) * STATE + bx * 128 + (r >> 7) * 32 +
             ((r >> 4) & 1) * 16 + (r & 15);
    }
    bSrcP[g] = Bsrc + wrow * KD + kT;
  }

  auto stage = [&](int k0n, unsigned bufoff) {
    gload16(aSrc + k0n, smem + bufoff + (unsigned)tid * 16u);
#pragma unroll
    for (int g = 0; g < 4; ++g)
      gload16(bSrcP[g] + k0n,
              smem + bufoff + 8192u + (unsigned)g * 8192u + (unsigned)tid * 16u);
  };

  f32x4 acc[4][8];
#pragma unroll
  for (int i = 0; i < 4; ++i)
#pragma unroll
    for (int j = 0; j < 8; ++j) acc[i][j] = f32x4{0.f, 0.f, 0.f, 0.f};

  short8_t av[4], bv[8];
  auto dsread = [&](unsigned bufoff) {
#pragma unroll
    for (int mf = 0; mf < 4; ++mf) av[mf] = LDS_V(smem + bufoff + aAddr + mf * 1024u);
#pragma unroll
    for (int nf = 0; nf < 8; ++nf) bv[nf] = LDS_V(smem + bufoff + bAddr + nf * 1024u);
  };
  auto domfma = [&]() {
    __builtin_amdgcn_s_setprio(1);
#pragma unroll
    for (int mf = 0; mf < 4; ++mf)
#pragma unroll
      for (int nf = 0; nf < 8; ++nf)
        acc[mf][nf] = mfma_bf16(av[mf], bv[nf], acc[mf][nf]);
    __builtin_amdgcn_s_setprio(0);
  };

  constexpr int NT = KD / 32;
  unsigned ur = 0u, un = 40960u, uf = 81920u;

  stage(0, ur);
  stage(32, un);
  asm volatile("s_waitcnt vmcnt(5)" ::: "memory");   // buf0's 5 loads retired
  __builtin_amdgcn_s_barrier();

#pragma unroll 1
  for (int t = 0; t < NT - 2; ++t) {
    dsread(ur);                                      // buf t resident (invariant)
    stage((t + 2) * 32, uf);
    asm volatile("s_waitcnt lgkmcnt(0)" ::: "memory"); // own reads done (WAR-safe)
    asm volatile("s_waitcnt vmcnt(5)" ::: "memory");   // buf t+1 landed
    __builtin_amdgcn_sched_barrier(0);
    __builtin_amdgcn_s_barrier();
    domfma();
    unsigned tmp = ur; ur = un; un = uf; uf = tmp;
  }
  // t = NT-2: nothing to stage; drain last tile's loads
  dsread(ur);
  asm volatile("s_waitcnt lgkmcnt(0)" ::: "memory");
  asm volatile("s_waitcnt vmcnt(0)" ::: "memory");
  __builtin_amdgcn_sched_barrier(0);
  __builtin_amdgcn_s_barrier();
  domfma();
  { unsigned tmp = ur; ur = un; un = uf; uf = tmp; }
  // t = NT-1: resident
  dsread(ur);
  domfma();

  // ---- epilogue ----
  const int lr0 = (l >> 4) << 2;
  const int rbase = m0 + wr * 64 + lr0;
  if constexpr (EPI <= 2) {
    const int cbase = bx * 512 + wc * 128 + (l & 15);
#pragma unroll
    for (int mf = 0; mf < 4; ++mf)
#pragma unroll
      for (int nf = 0; nf < 8; ++nf)
#pragma unroll
        for (int r = 0; r < 4; ++r) {
          const int row = rbase + mf * 16 + r;
          const int col = cbase + nf * 16;
          const size_t idx = (size_t)row * NCOLS + col;
          const float v = acc[mf][nf][r];
          if constexpr (EPI == 0) {
            bfout[idx] = f2bf(v);
          } else if constexpr (EPI == 1) {
            bfout[idx] = f2bf(v * sigmoidf_(v));
          } else {
            f32out[idx] = v;
          }
        }
  } else {
#pragma unroll
    for (int j = 0; j < 2; ++j) {
      const int s = bx * 128 + wc * 32 + j * 16 + (l & 15);
      const float dval = dvec[s];
#pragma unroll
      for (int mf = 0; mf < 4; ++mf)
#pragma unroll
        for (int r = 0; r < 4; ++r) {
          const int row = rbase + mf * 16 + r;
          const size_t idx = (size_t)row * STATE + s;
          const float a  = acc[mf][0 + j][r];
          const float b  = acc[mf][2 + j][r];
          const float c  = acc[mf][4 + j][r];
          const float dd = acc[mf][6 + j][r];
          const float uu = bf2f(ubf[idx]);
          const float hp = hprev[idx];
          const float h = sigmoidf_(a) * hp + tanhf_(b) * uu;
          f32out[idx] = h;                                               // h_t
          bfout[idx] = f2bf(tanhf_(c) * h + dval * sigmoidf_(dd) * uu);  // y
        }
    }
  }
}

extern "C" void kernel_launch(void* const* d_in, const int* in_sizes, int n_in,
                              void* d_out, int out_size, void* d_ws, size_t ws_size,
                              hipStream_t stream) {
  const float* x   = (const float*)d_in[0];
  const float* h0  = (const float*)d_in[1];
  const float* Win = (const float*)d_in[2];
  const float* Wsi = (const float*)d_in[3];
  const float* Wso = (const float*)d_in[4];
  const float* Wou = (const float*)d_in[5];
  const float* dv  = (const float*)d_in[6];
  float* out  = (float*)d_out;
  float* hout = out + (size_t)NB * DIMX;   // second output: h_t

  u16* ws = (u16*)d_ws;
  size_t o = 0;
  u16* xb   = ws + o; o += (size_t)NB * DIMX;        // x bf16
  u16* ub   = ws + o; o += (size_t)NB * STATE;       // u bf16
  u16* yb   = ws + o; o += (size_t)NB * STATE;       // y bf16
  u16* sh   = ws + o; o += (size_t)NB * SELH;        // sel_h bf16
  u16* wib  = ws + o; o += (size_t)STATE * DIMX;     // W_in bf16
  u16* wsib = ws + o; o += (size_t)SELH * DIMX;      // W_sel_in bf16
  u16* wsob = ws + o; o += (size_t)4 * STATE * SELH; // W_sel_out bf16
  u16* wob  = ws + o; o += (size_t)DIMX * STATE;     // W_out bf16

  k_convert5<<<2048, 256, 0, stream>>>(x,   xb,   NB * DIMX / 4,
                                       Win, wib,  STATE * DIMX / 4,
                                       Wsi, wsib, SELH * DIMX / 4,
                                       Wso, wsob, 4 * STATE * SELH / 4,
                                       Wou, wob,  DIMX * STATE / 4);

  const dim3 blk(512);
  // u = x @ W_in^T                (grid 4 x 128; B-panel 2MB, 1/XCD)
  k_gemm<0, DIMX, STATE><<<dim3(STATE / 512, NB / 128), blk, 0, stream>>>(
      xb, wib, nullptr, ub, nullptr, nullptr, nullptr);
  // sel_h = silu(x @ W_sel_in^T)  (grid 2 x 128)
  k_gemm<1, DIMX, SELH><<<dim3(SELH / 512, NB / 128), blk, 0, stream>>>(
      xb, wsib, nullptr, sh, nullptr, nullptr, nullptr);
  // FUSED 4-quad gate -> h_t (f32) + y (bf16)   (grid 16 x 128)
  k_gemm<3, SELH, 0><<<dim3(STATE / 128, NB / 128), blk, 0, stream>>>(
      sh, wsob, hout, yb, h0, ub, dv);
  // out = y @ W_out^T             (grid 4 x 128)
  k_gemm<2, STATE, DIMX><<<dim3(DIMX / 512, NB / 128), blk, 0, stream>>>(
      yb, wob, out, nullptr, nullptr, nullptr, nullptr);
}

// Round 16
// 686.122 us; speedup vs baseline: 1.1259x; 1.1259x over previous
//
#include <hip/hip_runtime.h>
#include <hip/hip_bf16.h>
#include <cstdint>

#define NB    16384
#define DIMX  2048
#define STATE 2048
#define SELH  1024

typedef unsigned short u16;
typedef short  short8_t __attribute__((ext_vector_type(8)));
typedef float  f32x4    __attribute__((ext_vector_type(4)));

__device__ __forceinline__ u16 f2bf(float f) {
  unsigned u = __builtin_bit_cast(unsigned, f);
  u += 0x7fffu + ((u >> 16) & 1u);   // RNE
  return (u16)(u >> 16);
}
__device__ __forceinline__ float bf2f(u16 h) {
  unsigned u = ((unsigned)h) << 16;
  return __builtin_bit_cast(float, u);
}
__device__ __forceinline__ float sigmoidf_(float x) { return 1.f / (1.f + __expf(-x)); }
__device__ __forceinline__ float tanhf_(float x)    { return 2.f / (1.f + __expf(-2.f * x)) - 1.f; }

__device__ __forceinline__ f32x4 mfma_bf16(short8_t a, short8_t b, f32x4 c) {
  return __builtin_amdgcn_mfma_f32_16x16x32_bf16(a, b, c, 0, 0, 0);
}

// ---- async global->LDS, 16B per lane ----
__device__ __forceinline__ void gload16(const void* g, const void* l) {
  __builtin_amdgcn_global_load_lds(
      (const __attribute__((address_space(1))) unsigned int*)(uintptr_t)g,
      (__attribute__((address_space(3))) unsigned int*)(unsigned int)(uintptr_t)l,
      16, 0, 0);
}

// aligned LDS vector read (ensure ds_read_b128)
#define LDS_V(p) (*(const short8_t*)__builtin_assume_aligned((const void*)(p), 16))

// ---- single-launch f32 -> bf16 convert over 5 segments ----
__global__ __launch_bounds__(256) void k_convert5(const float* __restrict__ s0, u16* __restrict__ d0, int n0,
                                                  const float* __restrict__ s1, u16* __restrict__ d1, int n1,
                                                  const float* __restrict__ s2, u16* __restrict__ d2, int n2,
                                                  const float* __restrict__ s3, u16* __restrict__ d3, int n3,
                                                  const float* __restrict__ s4, u16* __restrict__ d4, int n4) {
  const int base = blockIdx.x * blockDim.x + threadIdx.x;
  const int stride = gridDim.x * blockDim.x;
#define SEG(S, D, N)                                                     \
  for (int i = base; i < (N); i += stride) {                             \
    float4 v = ((const float4*)(S))[i];                                  \
    ushort4 o;                                                           \
    o.x = f2bf(v.x); o.y = f2bf(v.y); o.z = f2bf(v.z); o.w = f2bf(v.w);  \
    ((ushort4*)(D))[i] = o;                                              \
  }
  SEG(s0, d0, n0) SEG(s1, d1, n1) SEG(s2, d2, n2) SEG(s3, d3, n3) SEG(s4, d4, n4)
#undef SEG
}

// =====================================================================
// 256x256 GEMM (R9/R14 structure): 4 MFMA clusters per K-tile with
// cross-phase lookahead; 2 barriers/K-tile; counted vmcnt(2)/(4).
// R16 change (EPI==3 only): during the LAST K-tile, async-prefetch the
// block's h_prev slice (64KB f32) into the dead LDS buffer (buf0):
//   waves 0-3 -> [w*8192, +8192) in A0; waves 4-7 -> [65536+(w-4)*8192)
//   in B0. 8 gload16/wave; LASTT X2 vmcnt removed so prefetch stays in
//   flight under the final MFMA clusters; post-loop vmcnt(0) lands it
//   (wave-private region -> no barrier needed). Epilogue reads hp from
//   LDS; u reads batched into a register array up-front.
// EPI: 2 = f32 store | 3 = FUSED 4-quad gate -> h_t + y
//      5 = merged u|sel_h (bx < 8 -> u; else silu -> sel_h)
// =====================================================================
template <int EPI, int KD, int NCOLS>
__global__ __launch_bounds__(512, 2) void k_gemm256(const u16* __restrict__ A,
                                                    const u16* __restrict__ Bsrc,
                                                    float* __restrict__ f32out,
                                                    u16* __restrict__ bfout,
                                                    const float* __restrict__ hprev,
                                                    const u16* __restrict__ ubf,
                                                    const float* __restrict__ dvec,
                                                    u16* __restrict__ bfout2) {
  __shared__ __align__(16) char smem[131072];
  const int tid = threadIdx.x;
  const int w = tid >> 6, l = tid & 63;
  const int wr = w >> 2, wc = w & 3;
  const int bx = blockIdx.x, by = blockIdx.y;
  const int m0 = by * 256;

  // ---- ds_read bases (swizzled) ----
  const unsigned aAddr0 = (unsigned)(wr * 16384 + (l & 15) * 128 +
                                     (((l >> 4) * 16) ^ ((l & 7) << 4)));
  const unsigned aAddr1 = aAddr0 ^ 64u;
  const unsigned bAddr0 = (unsigned)(65536 + (wc * 64 + (l & 15)) * 64 +
                                     (((l >> 4) * 16) ^ ((l & 3) << 4)));
  const unsigned bAddr1 = bAddr0 + 16384u;

  // ---- staging: per-thread global sources (inverse-swizzled) ----
  const int rA = tid >> 3;
  const int kA = ((tid & 7) ^ ((tid >> 3) & 7)) * 8;
  const u16* aSrc = A + (size_t)(m0 + rA) * KD + kA;

  const int rB = tid >> 2;
  const int kB = ((tid & 3) ^ ((tid >> 2) & 3)) * 8;
  size_t bRow0, bRow1;
  if constexpr (EPI != 3) {
    bRow0 = (size_t)bx * 256 + rB;
    bRow1 = bRow0 + 128;
  } else {
    const int s0 = bx * 64;
    const int r1 = rB + 128;
    bRow0 = (size_t)((rB >> 4) & 3) * STATE + s0 + (rB >> 6) * 16 + (rB & 15);
    bRow1 = (size_t)((r1 >> 4) & 3) * STATE + s0 + (r1 >> 6) * 16 + (r1 & 15);
  }
  const u16* bSrc0 = Bsrc + bRow0 * KD + kB;
  const u16* bSrc1 = Bsrc + bRow1 * KD + kB;

  auto stageA = [&](int k0n, int rh, unsigned dstD) {
    const u16* sp = aSrc + (size_t)rh * 128 * KD + k0n;
    gload16(sp,           smem + dstD + (unsigned)rh * 16384u + (unsigned)tid * 16u);
    gload16(sp + 64 * KD, smem + dstD + (unsigned)rh * 16384u + 8192u + (unsigned)tid * 16u);
  };
  auto stageB = [&](int k0n, int kh, unsigned dstD) {
    const int kk = k0n + kh * 32;
    gload16(bSrc0 + kk, smem + 65536u + dstD + (unsigned)kh * 16384u + (unsigned)tid * 16u);
    gload16(bSrc1 + kk, smem + 65536u + dstD + (unsigned)kh * 16384u + 8192u + (unsigned)tid * 16u);
  };

  // ---- h_prev LDS prefetch (EPI==3 only; wave-private region) ----
  const unsigned hpBase = (w < 4) ? (unsigned)w * 8192u
                                  : 65536u + (unsigned)(w - 4) * 8192u;
  auto prefetchHP = [&]() {
    if constexpr (EPI == 3) {
      const float* hb = hprev + (size_t)(m0 + wr * 128 + (l >> 2)) * STATE +
                        bx * 64 + wc * 16 + (l & 3) * 4;
#pragma unroll
      for (int inst = 0; inst < 8; ++inst)
        gload16(hb + (size_t)inst * 16 * STATE,
                smem + hpBase + (unsigned)inst * 1024u + (unsigned)l * 16u);
    }
  };

  f32x4 acc[8][4];
#pragma unroll
  for (int i = 0; i < 8; ++i)
#pragma unroll
    for (int j = 0; j < 4; ++j) acc[i][j] = f32x4{0.f, 0.f, 0.f, 0.f};

  short8_t ava[8], avb[8], bv01a[2], bv23a[2], bv23b[2], bv01b[2];

#define KTILE(D, DO_STAGE, K0N, LASTT)                                         \
  {                                                                            \
    /* X1: tile boundary */                                                    \
    if (LASTT) { asm volatile("s_waitcnt vmcnt(0)" ::: "memory"); }            \
    else       { asm volatile("s_waitcnt vmcnt(2)" ::: "memory"); }            \
    __builtin_amdgcn_s_barrier();                                              \
    __builtin_amdgcn_sched_barrier(0);                                         \
    if (LASTT) prefetchHP();                                                   \
    bv01a[0] = LDS_V(smem + bAddr0 + (D) * 32768u);                            \
    bv01a[1] = LDS_V(smem + bAddr0 + (D) * 32768u + 1024u);                    \
    _Pragma("unroll") for (int mf = 0; mf < 8; ++mf)                           \
        ava[mf] = LDS_V(smem + aAddr0 + (D) * 32768u + mf * 2048u);            \
    if (DO_STAGE) { stageA(K0N, 0, (D ^ 1) * 32768u);                          \
                    stageA(K0N, 1, (D ^ 1) * 32768u); }                        \
    __builtin_amdgcn_s_setprio(1);                                             \
    _Pragma("unroll") for (int mf = 0; mf < 8; ++mf) {                         \
      acc[mf][0] = mfma_bf16(ava[mf], bv01a[0], acc[mf][0]);                   \
      acc[mf][1] = mfma_bf16(ava[mf], bv01a[1], acc[mf][1]);                   \
    }                                                                          \
    __builtin_amdgcn_s_setprio(0);                                             \
    /* X2 */                                                                   \
    if (!LASTT) { asm volatile("s_waitcnt vmcnt(4)" ::: "memory"); }           \
    __builtin_amdgcn_s_barrier();                                              \
    __builtin_amdgcn_sched_barrier(0);                                         \
    bv23a[0] = LDS_V(smem + bAddr0 + (D) * 32768u + 2048u);                    \
    bv23a[1] = LDS_V(smem + bAddr0 + (D) * 32768u + 3072u);                    \
    bv23b[0] = LDS_V(smem + bAddr1 + (D) * 32768u + 2048u);                    \
    bv23b[1] = LDS_V(smem + bAddr1 + (D) * 32768u + 3072u);                    \
    _Pragma("unroll") for (int mf = 0; mf < 8; ++mf)                           \
        avb[mf] = LDS_V(smem + aAddr1 + (D) * 32768u + mf * 2048u);            \
    if (DO_STAGE) { stageB(K0N, 0, (D ^ 1) * 32768u);                          \
                    stageB(K0N, 1, (D ^ 1) * 32768u); }                        \
    __builtin_amdgcn_s_setprio(1);                                             \
    _Pragma("unroll") for (int mf = 0; mf < 8; ++mf) {                         \
      acc[mf][2] = mfma_bf16(ava[mf], bv23a[0], acc[mf][2]);                   \
      acc[mf][3] = mfma_bf16(ava[mf], bv23a[1], acc[mf][3]);                   \
    }                                                                          \
    __builtin_amdgcn_s_setprio(0);                                             \
    /* X3 (no barrier) */                                                      \
    bv01b[0] = LDS_V(smem + bAddr1 + (D) * 32768u);                            \
    bv01b[1] = LDS_V(smem + bAddr1 + (D) * 32768u + 1024u);                    \
    __builtin_amdgcn_s_setprio(1);                                             \
    _Pragma("unroll") for (int mf = 0; mf < 8; ++mf) {                         \
      acc[mf][2] = mfma_bf16(avb[mf], bv23b[0], acc[mf][2]);                   \
      acc[mf][3] = mfma_bf16(avb[mf], bv23b[1], acc[mf][3]);                   \
    }                                                                          \
    __builtin_amdgcn_s_setprio(0);                                             \
    /* X4 (no barrier) */                                                      \
    __builtin_amdgcn_s_setprio(1);                                             \
    _Pragma("unroll") for (int mf = 0; mf < 8; ++mf) {                         \
      acc[mf][0] = mfma_bf16(avb[mf], bv01b[0], acc[mf][0]);                   \
      acc[mf][1] = mfma_bf16(avb[mf], bv01b[1], acc[mf][1]);                   \
    }                                                                          \
    __builtin_amdgcn_s_setprio(0);                                             \
  }

  // ---- prologue: stage T0 fully ----
  stageA(0, 0, 0u); stageA(0, 1, 0u); stageB(0, 0, 0u); stageB(0, 1, 0u);

  constexpr int NT = KD / 64;
  int k0 = 0;
#pragma unroll 1
  for (int T = 0; T < NT - 2; T += 2) {
    KTILE(0, true, k0 + 64, false);
    KTILE(1, true, k0 + 128, false);
    k0 += 128;
  }
  KTILE(0, true, k0 + 64, false);   // T = NT-2: stages last tile
  KTILE(1, false, 0, true);         // T = NT-1: no stage; issues hp prefetch

#undef KTILE

  // ---- epilogue ----
  const int rbase = m0 + wr * 128 + ((l >> 4) << 2);
  if constexpr (EPI == 2) {
    const int cbase = bx * 256 + wc * 64 + (l & 15);
#pragma unroll
    for (int mf = 0; mf < 8; ++mf)
#pragma unroll
      for (int nf = 0; nf < 4; ++nf)
#pragma unroll
        for (int r = 0; r < 4; ++r) {
          const int row = rbase + mf * 16 + r;
          const int col = cbase + nf * 16;
          f32out[(size_t)row * NCOLS + col] = acc[mf][nf][r];
        }
  } else if constexpr (EPI == 5) {
    const int cbase = bx * 256 + wc * 64 + (l & 15);
    if (bx < STATE / 256) {
#pragma unroll
      for (int mf = 0; mf < 8; ++mf)
#pragma unroll
        for (int nf = 0; nf < 4; ++nf)
#pragma unroll
          for (int r = 0; r < 4; ++r) {
            const int row = rbase + mf * 16 + r;
            const int col = cbase + nf * 16;
            bfout[(size_t)row * STATE + col] = f2bf(acc[mf][nf][r]);
          }
    } else {
#pragma unroll
      for (int mf = 0; mf < 8; ++mf)
#pragma unroll
        for (int nf = 0; nf < 4; ++nf)
#pragma unroll
          for (int r = 0; r < 4; ++r) {
            const int row = rbase + mf * 16 + r;
            const int col = cbase + nf * 16 - STATE;
            const float v = acc[mf][nf][r];
            bfout2[(size_t)row * SELH + col] = f2bf(v * sigmoidf_(v));
          }
    }
  } else {
    // land hp prefetch (own-wave DMA -> vmcnt(0) suffices, region private)
    asm volatile("s_waitcnt vmcnt(0)" ::: "memory");
    const int s = bx * 64 + wc * 16 + (l & 15);
    const float dval = dvec[s];
    const int lr0 = (l >> 4) << 2;
    // batch u loads first (L3-hot; breaks dependent-latency chains)
    u16 uuArr[8][4];
#pragma unroll
    for (int mf = 0; mf < 8; ++mf)
#pragma unroll
      for (int r = 0; r < 4; ++r)
        uuArr[mf][r] = ubf[(size_t)(rbase + mf * 16 + r) * STATE + s];
#pragma unroll
    for (int mf = 0; mf < 8; ++mf)
#pragma unroll
      for (int r = 0; r < 4; ++r) {
        const int row = rbase + mf * 16 + r;
        const size_t idx = (size_t)row * STATE + s;
        const float a  = acc[mf][0][r];
        const float b  = acc[mf][1][r];
        const float c  = acc[mf][2][r];
        const float dd = acc[mf][3][r];
        const float uu = bf2f(uuArr[mf][r]);
        const float hp = *(const float*)(smem + hpBase +
                          (unsigned)(mf * 16 + lr0 + r) * 64u +
                          (unsigned)(l & 15) * 4u);
        const float h = sigmoidf_(a) * hp + tanhf_(b) * uu;
        f32out[idx] = h;                                               // h_t
        bfout[idx] = f2bf(tanhf_(c) * h + dval * sigmoidf_(dd) * uu);  // y
      }
  }
}

extern "C" void kernel_launch(void* const* d_in, const int* in_sizes, int n_in,
                              void* d_out, int out_size, void* d_ws, size_t ws_size,
                              hipStream_t stream) {
  const float* x   = (const float*)d_in[0];
  const float* h0  = (const float*)d_in[1];
  const float* Win = (const float*)d_in[2];
  const float* Wsi = (const float*)d_in[3];
  const float* Wso = (const float*)d_in[4];
  const float* Wou = (const float*)d_in[5];
  const float* dv  = (const float*)d_in[6];
  float* out  = (float*)d_out;
  float* hout = out + (size_t)NB * DIMX;   // second output: h_t

  u16* ws = (u16*)d_ws;
  size_t o = 0;
  u16* xb   = ws + o; o += (size_t)NB * DIMX;        // x bf16
  u16* ub   = ws + o; o += (size_t)NB * STATE;       // u bf16
  u16* yb   = ws + o; o += (size_t)NB * STATE;       // y bf16
  u16* sh   = ws + o; o += (size_t)NB * SELH;        // sel_h bf16
  u16* wib  = ws + o; o += (size_t)STATE * DIMX;     // W_in bf16   } adjacent:
  u16* wsib = ws + o; o += (size_t)SELH * DIMX;      // W_sel_in    } 3072-row cat
  u16* wsob = ws + o; o += (size_t)4 * STATE * SELH; // W_sel_out bf16
  u16* wob  = ws + o; o += (size_t)DIMX * STATE;     // W_out bf16

  k_convert5<<<2048, 256, 0, stream>>>(x,   xb,   NB * DIMX / 4,
                                       Win, wib,  STATE * DIMX / 4,
                                       Wsi, wsib, SELH * DIMX / 4,
                                       Wso, wsob, 4 * STATE * SELH / 4,
                                       Wou, wob,  DIMX * STATE / 4);

  const dim3 blk(512);
  // MERGED: [u | sel_h] = x @ [W_in; W_sel_in]^T  (N = 3072)
  k_gemm256<5, DIMX, 0><<<dim3((STATE + SELH) / 256, NB / 256), blk, 0, stream>>>(
      xb, wib, nullptr, ub, nullptr, nullptr, nullptr, sh);
  // FUSED: all 4 quadrants of sel -> h_t (f32) AND y (bf16) in one pass
  k_gemm256<3, SELH, 0><<<dim3(STATE / 64, NB / 256), blk, 0, stream>>>(
      sh, wsob, hout, yb, h0, ub, dv, nullptr);
  // out = y @ W_out^T
  k_gemm256<2, STATE, DIMX><<<dim3(DIMX / 256, NB / 256), blk, 0, stream>>>(
      yb, wob, out, nullptr, nullptr, nullptr, nullptr, nullptr);
}